// Round 6
// baseline (375.378 us; speedup 1.0000x reference)
//
#include <hip/hip_runtime.h>
#include <math.h>

// ---------------------------------------------------------------------------
// IPOT on MI355X — round 6.
// Math (exact, verified absmax 0.0 R1/R2/R4/R5):
//   Cl = -C;  M_t = exp((t+1)*Cl) = E1^(t+1), E1 = exp(Cl)
//   row:  r_i = sum_j M_t(i,j) s_j ; a = 1/(n r)
//   col:  c_j = sum_i M_t(i,j) a_i ; b = 1/c (2^10 inj); s' = b^2/b_prev/1024
//   final G(A,B) = (1/(256*1024)) sum_k P(k,A) R(k,B)
// R6 (kill R5's 32-way LDS conflicts + per-round LDS round trip):
//   - ownership flip: wave owns col-quarter, THREAD owns all 32 rows x 4 cols
//     (E[32][4] = 128 VGPR). s is computed/consumed in registers (no LDS s).
//   - col phase fully thread-local -> direct atomicAdd (chain 8, NREP=4).
//   - E updated multiplicatively (E *= E1); P row-sums pre-accumulated, C
//     registers freed. 128 mults/round instead of 128 exps.
//   - all-thread counter polling (wave-coalesced) — no tid0 broadcast.
//   - per-round intra-WG traffic: one 32-reg butterfly + rws[4][32]+aL[32].
// ---------------------------------------------------------------------------

#define NWG 32
#define TPB 256
#define NIT 50
#define NREP 4

typedef unsigned long long ull;

// ws offsets in floats
constexpr int CL_OFF   = 0;                           // -C [1024*1024]
constexpr int CVEC_OFF = 1024 * 1024;                 // [3][NREP][1024]
constexpr int CNT_OFF  = CVEC_OFF + 3 * NREP * 1024;  // 4 group counters (pad 16)
// total ~ 4.05 MB

// ---------------- C = 1 - xhat yhat^T (norms fused) ; Cl = -C ---------------
__global__ __launch_bounds__(256) void k_gemm(const float* __restrict__ X,
                                              const float* __restrict__ Y,
                                              float* __restrict__ ws) {
    __shared__ float As[32][68];
    __shared__ float Bs[32][68];
    __shared__ float nX[64], nY[64];
    float* Cl = ws + CL_OFF;

    int tid = threadIdx.x;
    int tx = tid & 15, ty = tid >> 4;
    int bx = blockIdx.x, by = blockIdx.y;
    int lr0 = tid >> 3;          // 0..31
    int kq  = (tid & 7) * 4;     // 0..28

    float acc[4][4] = {};
    float sx0 = 0.f, sx1 = 0.f, sy0 = 0.f, sy1 = 0.f;
    for (int k0 = 0; k0 < 512; k0 += 32) {
        float4 xa = *(const float4*)(X + (size_t)(by * 64 + lr0) * 512 + k0 + kq);
        float4 xb = *(const float4*)(X + (size_t)(by * 64 + lr0 + 32) * 512 + k0 + kq);
        float4 ya = *(const float4*)(Y + (size_t)(bx * 64 + lr0) * 512 + k0 + kq);
        float4 yb = *(const float4*)(Y + (size_t)(bx * 64 + lr0 + 32) * 512 + k0 + kq);
        sx0 += xa.x * xa.x + xa.y * xa.y + xa.z * xa.z + xa.w * xa.w;
        sx1 += xb.x * xb.x + xb.y * xb.y + xb.z * xb.z + xb.w * xb.w;
        sy0 += ya.x * ya.x + ya.y * ya.y + ya.z * ya.z + ya.w * ya.w;
        sy1 += yb.x * yb.x + yb.y * yb.y + yb.z * yb.z + yb.w * yb.w;
        As[kq + 0][lr0] = xa.x; As[kq + 1][lr0] = xa.y;
        As[kq + 2][lr0] = xa.z; As[kq + 3][lr0] = xa.w;
        As[kq + 0][lr0 + 32] = xb.x; As[kq + 1][lr0 + 32] = xb.y;
        As[kq + 2][lr0 + 32] = xb.z; As[kq + 3][lr0 + 32] = xb.w;
        Bs[kq + 0][lr0] = ya.x; Bs[kq + 1][lr0] = ya.y;
        Bs[kq + 2][lr0] = ya.z; Bs[kq + 3][lr0] = ya.w;
        Bs[kq + 0][lr0 + 32] = yb.x; Bs[kq + 1][lr0 + 32] = yb.y;
        Bs[kq + 2][lr0 + 32] = yb.z; Bs[kq + 3][lr0 + 32] = yb.w;
        __syncthreads();
#pragma unroll
        for (int kk = 0; kk < 32; ++kk) {
            float4 a4 = *(const float4*)&As[kk][4 * ty];
            float4 b4 = *(const float4*)&Bs[kk][4 * tx];
            float av[4] = {a4.x, a4.y, a4.z, a4.w};
            float bv[4] = {b4.x, b4.y, b4.z, b4.w};
#pragma unroll
            for (int r = 0; r < 4; ++r)
#pragma unroll
                for (int q = 0; q < 4; ++q) acc[r][q] += av[r] * bv[q];
        }
        __syncthreads();
    }
#pragma unroll
    for (int m = 1; m < 8; m <<= 1) {
        sx0 += __shfl_xor(sx0, m, 64);
        sx1 += __shfl_xor(sx1, m, 64);
        sy0 += __shfl_xor(sy0, m, 64);
        sy1 += __shfl_xor(sy1, m, 64);
    }
    if ((tid & 7) == 0) {
        nX[lr0] = sx0; nX[lr0 + 32] = sx1;
        nY[lr0] = sy0; nY[lr0 + 32] = sy1;
    }
    __syncthreads();

    int i0 = by * 64 + 4 * ty, j0 = bx * 64 + 4 * tx;
    float vy[4];
#pragma unroll
    for (int q = 0; q < 4; ++q) vy[q] = 1.0f / sqrtf(nY[4 * tx + q]);
#pragma unroll
    for (int r = 0; r < 4; ++r) {
        float vx = 1.0f / sqrtf(nX[4 * ty + r]);
        float4 o;
        o.x = acc[r][0] * vx * vy[0] - 1.0f;  // Cl = dot - 1 = -C
        o.y = acc[r][1] * vx * vy[1] - 1.0f;
        o.z = acc[r][2] * vx * vy[2] - 1.0f;
        o.w = acc[r][3] * vx * vy[3] - 1.0f;
        *(float4*)(Cl + (size_t)(i0 + r) * 1024 + j0) = o;
    }
}

__device__ __forceinline__ float f_lo(ull u) { return __uint_as_float((unsigned)u); }
__device__ __forceinline__ float f_hi(ull u) { return __uint_as_float((unsigned)(u >> 32)); }

// ---------------------- persistent IPOT iteration --------------------------
__global__ __launch_bounds__(256, 1) void k_ipot(float* __restrict__ ws,
                                                 float* __restrict__ out) {
    __shared__ float rws[4][32];
    __shared__ float aLs[32];
    __shared__ float PsRs[4096];  // epilogue: Ps[0..2047] Rs[2048..4095]
    __shared__ float twv[4];

    const int g = blockIdx.x, tid = threadIdx.x;
    const int rs = tid >> 6, lane = tid & 63;
    const int j0 = rs * 256 + lane * 4;     // first of this thread's 4 cols
    float* Cl   = ws + CL_OFF;
    float* cvec = ws + CVEC_OFF;
    unsigned* grp = (unsigned*)(ws + CNT_OFF);

    // prologue: E1 = exp(Cl) for all 32 rows x own 4 cols; P row-sum partials
    float E1[32][4], E[32][4], Pp[32];
#pragma unroll
    for (int i = 0; i < 32; ++i) {
        float4 c = *(const float4*)(Cl + (size_t)(g * 32 + i) * 1024 + j0);
        Pp[i] = c.x + c.y + c.z + c.w;           // sum of Cl (negate later)
        E1[i][0] = __expf(c.x); E1[i][1] = __expf(c.y);
        E1[i][2] = __expf(c.z); E1[i][3] = __expf(c.w);
        E[i][0] = E1[i][0]; E[i][1] = E1[i][1];
        E[i][2] = E1[i][2]; E[i][3] = E1[i][3];
    }
    float bv[4] = {1.0f, 1.0f, 1.0f, 1.0f};
    float al[32];

    for (int t = 0; t < NIT; ++t) {
        float s0, s1, s2, s3;
        if (t == 0) {
            s0 = s1 = s2 = s3 = 1.0f / 1024.0f;
        } else {
            unsigned tgt = (unsigned)t * 8u;     // all WGs done round t-1
            long gd = 0;
            while (__hip_atomic_load(&grp[0], __ATOMIC_RELAXED, __HIP_MEMORY_SCOPE_AGENT) < tgt ||
                   __hip_atomic_load(&grp[1], __ATOMIC_RELAXED, __HIP_MEMORY_SCOPE_AGENT) < tgt ||
                   __hip_atomic_load(&grp[2], __ATOMIC_RELAXED, __HIP_MEMORY_SCOPE_AGENT) < tgt ||
                   __hip_atomic_load(&grp[3], __ATOMIC_RELAXED, __HIP_MEMORY_SCOPE_AGENT) < tgt) {
                __builtin_amdgcn_s_sleep(1);
                if (++gd > 3000000) break;       // anti-hang bailout
            }
            // readback own 4 cols across 4 replicas (8B coherent loads)
            const ull* rb = (const ull*)(cvec + ((t + 2) % 3) * (NREP * 1024)) + (j0 >> 1);
            ull a0 = __hip_atomic_load(rb + 0,    __ATOMIC_RELAXED, __HIP_MEMORY_SCOPE_AGENT);
            ull a1 = __hip_atomic_load(rb + 1,    __ATOMIC_RELAXED, __HIP_MEMORY_SCOPE_AGENT);
            ull b0 = __hip_atomic_load(rb + 512,  __ATOMIC_RELAXED, __HIP_MEMORY_SCOPE_AGENT);
            ull b1 = __hip_atomic_load(rb + 513,  __ATOMIC_RELAXED, __HIP_MEMORY_SCOPE_AGENT);
            ull c0 = __hip_atomic_load(rb + 1024, __ATOMIC_RELAXED, __HIP_MEMORY_SCOPE_AGENT);
            ull c1 = __hip_atomic_load(rb + 1025, __ATOMIC_RELAXED, __HIP_MEMORY_SCOPE_AGENT);
            ull d0 = __hip_atomic_load(rb + 1536, __ATOMIC_RELAXED, __HIP_MEMORY_SCOPE_AGENT);
            ull d1 = __hip_atomic_load(rb + 1537, __ATOMIC_RELAXED, __HIP_MEMORY_SCOPE_AGENT);
            if (t >= 2 && tid < 64) {            // zero buffer read at t-1
                ull* zb = (ull*)(cvec + ((t + 1) % 3) * (NREP * 1024)) + g * 64 + tid;
                __hip_atomic_store(zb, 0ull, __ATOMIC_RELAXED, __HIP_MEMORY_SCOPE_AGENT);
            }
            float cc0 = f_lo(a0) + f_lo(b0) + f_lo(c0) + f_lo(d0);
            float cc1 = f_hi(a0) + f_hi(b0) + f_hi(c0) + f_hi(d0);
            float cc2 = f_lo(a1) + f_lo(b1) + f_lo(c1) + f_lo(d1);
            float cc3 = f_hi(a1) + f_hi(b1) + f_hi(c1) + f_hi(d1);
            float nb0 = 1.0f / cc0, nb1 = 1.0f / cc1;        // 2^10 inj
            float nb2 = 1.0f / cc2, nb3 = 1.0f / cc3;
            s0 = nb0 * nb0 / bv[0] * (1.0f / 1024.0f); bv[0] = nb0;  // 2^-10 inj
            s1 = nb1 * nb1 / bv[1] * (1.0f / 1024.0f); bv[1] = nb1;
            s2 = nb2 * nb2 / bv[2] * (1.0f / 1024.0f); bv[2] = nb2;
            s3 = nb3 * nb3 / bv[3] * (1.0f / 1024.0f); bv[3] = nb3;
        }

        // row partials over own 4 cols, butterfly over wave (256 cols/wave)
        float rp[32];
#pragma unroll
        for (int i = 0; i < 32; ++i)
            rp[i] = E[i][0] * s0 + E[i][1] * s1 + E[i][2] * s2 + E[i][3] * s3;
#pragma unroll
        for (int m = 1; m < 64; m <<= 1)
#pragma unroll
            for (int i = 0; i < 32; ++i) rp[i] += __shfl_xor(rp[i], m, 64);
        if (lane == 0) {
#pragma unroll
            for (int q = 0; q < 8; ++q)
                *(float4*)&rws[rs][4 * q] =
                    make_float4(rp[4*q], rp[4*q+1], rp[4*q+2], rp[4*q+3]);
        }
        __syncthreads();
        if (tid < 32)
            aLs[tid] = 1.0f / (1024.0f * (rws[0][tid] + rws[1][tid] +
                                          rws[2][tid] + rws[3][tid]));
        __syncthreads();
#pragma unroll
        for (int q = 0; q < 8; ++q) {
            float4 a4 = *(const float4*)&aLs[4 * q];
            al[4*q] = a4.x; al[4*q+1] = a4.y; al[4*q+2] = a4.z; al[4*q+3] = a4.w;
        }

        // col phase: fully thread-local, direct atomicAdd (replica g&3)
        float p0 = 0.f, p1 = 0.f, p2 = 0.f, p3 = 0.f;
#pragma unroll
        for (int i = 0; i < 32; ++i) {
            float ai = al[i];
            p0 += E[i][0] * ai; p1 += E[i][1] * ai;
            p2 += E[i][2] * ai; p3 += E[i][3] * ai;
        }
        float* wb = cvec + (t % 3) * (NREP * 1024) + (g & 3) * 1024 + j0;
        atomicAdd(wb + 0, p0);
        atomicAdd(wb + 1, p1);
        atomicAdd(wb + 2, p2);
        atomicAdd(wb + 3, p3);
        __syncthreads();  // per-thread vmcnt(0) drain: all 1024 adds at LLC
        if (tid == 0)
            __hip_atomic_fetch_add(&grp[g >> 3], 1u, __ATOMIC_RELAXED,
                                   __HIP_MEMORY_SCOPE_AGENT);

        if (t < NIT - 1) {  // E_{t+1} = E_t * E1 (overlaps WG skew)
#pragma unroll
            for (int i = 0; i < 32; ++i) {
                E[i][0] *= E1[i][0]; E[i][1] *= E1[i][1];
                E[i][2] *= E1[i][2]; E[i][3] *= E1[i][3];
            }
        }
    }

    // ---------------- epilogue: E = exp(50*Cl), al = round-49 a -------------
    {
        unsigned tgt = (unsigned)NIT * 8u;
        long gd = 0;
        while (__hip_atomic_load(&grp[0], __ATOMIC_RELAXED, __HIP_MEMORY_SCOPE_AGENT) < tgt ||
               __hip_atomic_load(&grp[1], __ATOMIC_RELAXED, __HIP_MEMORY_SCOPE_AGENT) < tgt ||
               __hip_atomic_load(&grp[2], __ATOMIC_RELAXED, __HIP_MEMORY_SCOPE_AGENT) < tgt ||
               __hip_atomic_load(&grp[3], __ATOMIC_RELAXED, __HIP_MEMORY_SCOPE_AGENT) < tgt) {
            __builtin_amdgcn_s_sleep(1);
            if (++gd > 3000000) break;
        }
    }
    float bl[4];
    {   // final b for own 4 cols (round-49 col sums)
        const ull* rb = (const ull*)(cvec + ((NIT - 1) % 3) * (NREP * 1024)) + (j0 >> 1);
        ull a0 = __hip_atomic_load(rb + 0,    __ATOMIC_RELAXED, __HIP_MEMORY_SCOPE_AGENT);
        ull a1 = __hip_atomic_load(rb + 1,    __ATOMIC_RELAXED, __HIP_MEMORY_SCOPE_AGENT);
        ull b0 = __hip_atomic_load(rb + 512,  __ATOMIC_RELAXED, __HIP_MEMORY_SCOPE_AGENT);
        ull b1 = __hip_atomic_load(rb + 513,  __ATOMIC_RELAXED, __HIP_MEMORY_SCOPE_AGENT);
        ull c0 = __hip_atomic_load(rb + 1024, __ATOMIC_RELAXED, __HIP_MEMORY_SCOPE_AGENT);
        ull c1 = __hip_atomic_load(rb + 1025, __ATOMIC_RELAXED, __HIP_MEMORY_SCOPE_AGENT);
        ull d0 = __hip_atomic_load(rb + 1536, __ATOMIC_RELAXED, __HIP_MEMORY_SCOPE_AGENT);
        ull d1 = __hip_atomic_load(rb + 1537, __ATOMIC_RELAXED, __HIP_MEMORY_SCOPE_AGENT);
        bl[0] = 1.0f / (f_lo(a0) + f_lo(b0) + f_lo(c0) + f_lo(d0));
        bl[1] = 1.0f / (f_hi(a0) + f_hi(b0) + f_hi(c0) + f_hi(d0));
        bl[2] = 1.0f / (f_lo(a1) + f_lo(b1) + f_lo(c1) + f_lo(d1));
        bl[3] = 1.0f / (f_hi(a1) + f_hi(b1) + f_hi(c1) + f_hi(d1));
    }

    // P(k,A), R(k,B): reduce own-4-col partials over the 4 lanes per block
    float* Ps = PsRs;           // [32][64]
    float* Rs = PsRs + 2048;    // [32][64]
    float Pl[32], Rl[32];
#pragma unroll
    for (int k = 0; k < 32; ++k) {
        Pl[k] = Pp[k];
        Rl[k] = E[k][0] * bl[0] + E[k][1] * bl[1] +
                E[k][2] * bl[2] + E[k][3] * bl[3];
    }
#pragma unroll
    for (int m = 1; m < 4; m <<= 1)
#pragma unroll
        for (int k = 0; k < 32; ++k) {
            Pl[k] += __shfl_xor(Pl[k], m, 64);
            Rl[k] += __shfl_xor(Rl[k], m, 64);
        }
    if ((lane & 3) == 0) {
        int A = rs * 16 + (lane >> 2);
#pragma unroll
        for (int k = 0; k < 32; ++k) {
            Ps[k * 64 + A] = -Pl[k];          // C = -Cl
            Rs[k * 64 + A] = al[k] * Rl[k];   // al = round-49 a
        }
    }
    __syncthreads();

    // G partial (this WG's 32 k-rows) -> atomicAdd into zeroed d_out
    float Rk[32];
#pragma unroll
    for (int k = 0; k < 32; ++k) Rk[k] = Rs[k * 64 + lane];  // B = lane
    const float sc = 1.0f / (256.0f * 1024.0f);
    float tsum = 0.0f;
#pragma unroll
    for (int q = 0; q < 16; ++q) {
        int o = tid + 256 * q;
        int A = 4 * q + rs;                  // = o >> 6
        float acc = 0.0f;
#pragma unroll
        for (int k = 0; k < 32; ++k) acc += Ps[k * 64 + A] * Rk[k];
        float val = acc * sc;
        atomicAdd(out + o, val);
        if (A == lane) tsum += val;
    }
#pragma unroll
    for (int m = 1; m < 64; m <<= 1) tsum += __shfl_xor(tsum, m, 64);
    if (lane == 0) twv[rs] = tsum;
    __syncthreads();
    if (tid == 0) atomicAdd(out + 4096, twv[0] + twv[1] + twv[2] + twv[3]);
}

// ---------------------------------------------------------------------------
extern "C" void kernel_launch(void* const* d_in, const int* in_sizes, int n_in,
                              void* d_out, int out_size, void* d_ws, size_t ws_size,
                              hipStream_t stream) {
    const float* X = (const float*)d_in[0];  // t_prob [1024,512]
    const float* Y = (const float*)d_in[1];  // v_prob [1024,512]
    float* out = (float*)d_out;              // [64*64 + 1]
    float* ws  = (float*)d_ws;

    // zero cvec + counters (ws poisoned each call), zero d_out
    (void)hipMemsetAsync((char*)d_ws + (size_t)CVEC_OFF * 4, 0,
                         (3 * NREP * 1024 + 16) * 4, stream);
    (void)hipMemsetAsync(d_out, 0, (size_t)out_size * 4, stream);

    k_gemm<<<dim3(16, 16), 256, 0, stream>>>(X, Y, ws);
    k_ipot<<<NWG, TPB, 0, stream>>>(ws, out);
}

// Round 7
// 346.825 us; speedup vs baseline: 1.0823x; 1.0823x over previous
//
#include <hip/hip_runtime.h>
#include <math.h>

// ---------------------------------------------------------------------------
// IPOT on MI355X — round 7.
// Math (exact, verified absmax 0.0 R1..R6):
//   Cl = -C;  M_t = exp((t+1)*Cl) = E1^(t+1), E1 = exp(Cl)
//   row:  r_i = sum_j M_t(i,j) s_j ; a = 1/(n r)
//   col:  c_j = sum_i M_t(i,j) a_i ; b = 1/c (2^10 inj); s' = b^2/b_prev/1024
//   final G(A,B) = (1/(256*1024)) sum_k P(k,A) R(k,B)
// R7 (fix the sync primitive — R6's real bottleneck):
//   - poll: lanes 0..3 load the 4 counters CONCURRENTLY + __all ballot
//     (was: short-circuit || => 4 DEPENDENT LLC round trips per iteration).
//   - per-wave polling (128 pollers, no broadcast barrier); counters padded
//     to separate 128B lines so increments don't fight polls.
//   - register-splitting butterfly: 32 rows over 64 lanes in 32 shuffles
//     (was 192); lane l ends with row (l&31).
//   - E *= E1 moved before the drain barrier (overlaps atomic chain).
// ---------------------------------------------------------------------------

#define NWG 32
#define TPB 256
#define NIT 50
#define NREP 4

typedef unsigned long long ull;

// ws offsets in floats
constexpr int CL_OFF   = 0;                           // -C [1024*1024]
constexpr int CVEC_OFF = 1024 * 1024;                 // [3][NREP][1024]
constexpr int CNT_OFF  = CVEC_OFF + 3 * NREP * 1024;  // 4 counters, 32-float stride
// total ~ 4.05 MB

// ---------------- C = 1 - xhat yhat^T (norms fused) ; Cl = -C ---------------
__global__ __launch_bounds__(256) void k_gemm(const float* __restrict__ X,
                                              const float* __restrict__ Y,
                                              float* __restrict__ ws) {
    __shared__ float As[32][68];
    __shared__ float Bs[32][68];
    __shared__ float nX[64], nY[64];
    float* Cl = ws + CL_OFF;

    int tid = threadIdx.x;
    int tx = tid & 15, ty = tid >> 4;
    int bx = blockIdx.x, by = blockIdx.y;
    int lr0 = tid >> 3;          // 0..31
    int kq  = (tid & 7) * 4;     // 0..28

    float acc[4][4] = {};
    float sx0 = 0.f, sx1 = 0.f, sy0 = 0.f, sy1 = 0.f;
    for (int k0 = 0; k0 < 512; k0 += 32) {
        float4 xa = *(const float4*)(X + (size_t)(by * 64 + lr0) * 512 + k0 + kq);
        float4 xb = *(const float4*)(X + (size_t)(by * 64 + lr0 + 32) * 512 + k0 + kq);
        float4 ya = *(const float4*)(Y + (size_t)(bx * 64 + lr0) * 512 + k0 + kq);
        float4 yb = *(const float4*)(Y + (size_t)(bx * 64 + lr0 + 32) * 512 + k0 + kq);
        sx0 += xa.x * xa.x + xa.y * xa.y + xa.z * xa.z + xa.w * xa.w;
        sx1 += xb.x * xb.x + xb.y * xb.y + xb.z * xb.z + xb.w * xb.w;
        sy0 += ya.x * ya.x + ya.y * ya.y + ya.z * ya.z + ya.w * ya.w;
        sy1 += yb.x * yb.x + yb.y * yb.y + yb.z * yb.z + yb.w * yb.w;
        As[kq + 0][lr0] = xa.x; As[kq + 1][lr0] = xa.y;
        As[kq + 2][lr0] = xa.z; As[kq + 3][lr0] = xa.w;
        As[kq + 0][lr0 + 32] = xb.x; As[kq + 1][lr0 + 32] = xb.y;
        As[kq + 2][lr0 + 32] = xb.z; As[kq + 3][lr0 + 32] = xb.w;
        Bs[kq + 0][lr0] = ya.x; Bs[kq + 1][lr0] = ya.y;
        Bs[kq + 2][lr0] = ya.z; Bs[kq + 3][lr0] = ya.w;
        Bs[kq + 0][lr0 + 32] = yb.x; Bs[kq + 1][lr0 + 32] = yb.y;
        Bs[kq + 2][lr0 + 32] = yb.z; Bs[kq + 3][lr0 + 32] = yb.w;
        __syncthreads();
#pragma unroll
        for (int kk = 0; kk < 32; ++kk) {
            float4 a4 = *(const float4*)&As[kk][4 * ty];
            float4 b4 = *(const float4*)&Bs[kk][4 * tx];
            float av[4] = {a4.x, a4.y, a4.z, a4.w};
            float bv[4] = {b4.x, b4.y, b4.z, b4.w};
#pragma unroll
            for (int r = 0; r < 4; ++r)
#pragma unroll
                for (int q = 0; q < 4; ++q) acc[r][q] += av[r] * bv[q];
        }
        __syncthreads();
    }
#pragma unroll
    for (int m = 1; m < 8; m <<= 1) {
        sx0 += __shfl_xor(sx0, m, 64);
        sx1 += __shfl_xor(sx1, m, 64);
        sy0 += __shfl_xor(sy0, m, 64);
        sy1 += __shfl_xor(sy1, m, 64);
    }
    if ((tid & 7) == 0) {
        nX[lr0] = sx0; nX[lr0 + 32] = sx1;
        nY[lr0] = sy0; nY[lr0 + 32] = sy1;
    }
    __syncthreads();

    int i0 = by * 64 + 4 * ty, j0 = bx * 64 + 4 * tx;
    float vy[4];
#pragma unroll
    for (int q = 0; q < 4; ++q) vy[q] = 1.0f / sqrtf(nY[4 * tx + q]);
#pragma unroll
    for (int r = 0; r < 4; ++r) {
        float vx = 1.0f / sqrtf(nX[4 * ty + r]);
        float4 o;
        o.x = acc[r][0] * vx * vy[0] - 1.0f;  // Cl = dot - 1 = -C
        o.y = acc[r][1] * vx * vy[1] - 1.0f;
        o.z = acc[r][2] * vx * vy[2] - 1.0f;
        o.w = acc[r][3] * vx * vy[3] - 1.0f;
        *(float4*)(Cl + (size_t)(i0 + r) * 1024 + j0) = o;
    }
}

__device__ __forceinline__ float f_lo(ull u) { return __uint_as_float((unsigned)u); }
__device__ __forceinline__ float f_hi(ull u) { return __uint_as_float((unsigned)(u >> 32)); }

// wave-convergent parallel poll: lanes 0..3 each watch one padded counter
__device__ __forceinline__ void wavepoll(const unsigned* cnt, int lane,
                                         unsigned tgt) {
    int done = (lane < 4)
        ? (__hip_atomic_load(&cnt[lane * 32], __ATOMIC_RELAXED,
                             __HIP_MEMORY_SCOPE_AGENT) >= tgt) : 1;
    long gd = 0;
    while (!__all(done)) {
        __builtin_amdgcn_s_sleep(1);
        if (lane < 4)
            done = (__hip_atomic_load(&cnt[lane * 32], __ATOMIC_RELAXED,
                                      __HIP_MEMORY_SCOPE_AGENT) >= tgt);
        if (++gd > 2000000) break;  // anti-hang bailout
    }
}

// ---------------------- persistent IPOT iteration --------------------------
__global__ __launch_bounds__(256, 1) void k_ipot(float* __restrict__ ws,
                                                 float* __restrict__ out) {
    __shared__ float rws[4][32];
    __shared__ float aLs[32];
    __shared__ float PsRs[4096];  // epilogue: Ps[0..2047] Rs[2048..4095]
    __shared__ float twv[4];

    const int g = blockIdx.x, tid = threadIdx.x;
    const int rs = tid >> 6, lane = tid & 63;
    const int j0 = rs * 256 + lane * 4;     // first of this thread's 4 cols
    float* Cl   = ws + CL_OFF;
    float* cvec = ws + CVEC_OFF;
    unsigned* cnt = (unsigned*)(ws + CNT_OFF);  // stride-32 padded counters

    // prologue: E1 = exp(Cl) for all 32 rows x own 4 cols; P row-sum partials
    float E1[32][4], E[32][4], Pp[32];
#pragma unroll
    for (int i = 0; i < 32; ++i) {
        float4 c = *(const float4*)(Cl + (size_t)(g * 32 + i) * 1024 + j0);
        Pp[i] = c.x + c.y + c.z + c.w;           // sum of Cl (negate later)
        E1[i][0] = __expf(c.x); E1[i][1] = __expf(c.y);
        E1[i][2] = __expf(c.z); E1[i][3] = __expf(c.w);
        E[i][0] = E1[i][0]; E[i][1] = E1[i][1];
        E[i][2] = E1[i][2]; E[i][3] = E1[i][3];
    }
    float bv[4] = {1.0f, 1.0f, 1.0f, 1.0f};
    float al[32];

    for (int t = 0; t < NIT; ++t) {
        float s0, s1, s2, s3;
        if (t == 0) {
            s0 = s1 = s2 = s3 = 1.0f / 1024.0f;
        } else {
            wavepoll(cnt, lane, (unsigned)t * 8u);  // all WGs done round t-1
            // readback own 4 cols across 4 replicas (8 parallel 8B loads)
            const ull* rb = (const ull*)(cvec + ((t + 2) % 3) * (NREP * 1024)) + (j0 >> 1);
            ull a0 = __hip_atomic_load(rb + 0,    __ATOMIC_RELAXED, __HIP_MEMORY_SCOPE_AGENT);
            ull a1 = __hip_atomic_load(rb + 1,    __ATOMIC_RELAXED, __HIP_MEMORY_SCOPE_AGENT);
            ull b0 = __hip_atomic_load(rb + 512,  __ATOMIC_RELAXED, __HIP_MEMORY_SCOPE_AGENT);
            ull b1 = __hip_atomic_load(rb + 513,  __ATOMIC_RELAXED, __HIP_MEMORY_SCOPE_AGENT);
            ull c0 = __hip_atomic_load(rb + 1024, __ATOMIC_RELAXED, __HIP_MEMORY_SCOPE_AGENT);
            ull c1 = __hip_atomic_load(rb + 1025, __ATOMIC_RELAXED, __HIP_MEMORY_SCOPE_AGENT);
            ull d0 = __hip_atomic_load(rb + 1536, __ATOMIC_RELAXED, __HIP_MEMORY_SCOPE_AGENT);
            ull d1 = __hip_atomic_load(rb + 1537, __ATOMIC_RELAXED, __HIP_MEMORY_SCOPE_AGENT);
            if (t >= 2 && tid < 64) {            // zero buffer read at t-1
                ull* zb = (ull*)(cvec + ((t + 1) % 3) * (NREP * 1024)) + g * 64 + tid;
                __hip_atomic_store(zb, 0ull, __ATOMIC_RELAXED, __HIP_MEMORY_SCOPE_AGENT);
            }
            float cc0 = f_lo(a0) + f_lo(b0) + f_lo(c0) + f_lo(d0);
            float cc1 = f_hi(a0) + f_hi(b0) + f_hi(c0) + f_hi(d0);
            float cc2 = f_lo(a1) + f_lo(b1) + f_lo(c1) + f_lo(d1);
            float cc3 = f_hi(a1) + f_hi(b1) + f_hi(c1) + f_hi(d1);
            float nb0 = 1.0f / cc0, nb1 = 1.0f / cc1;        // 2^10 inj
            float nb2 = 1.0f / cc2, nb3 = 1.0f / cc3;
            s0 = nb0 * nb0 / bv[0] * (1.0f / 1024.0f); bv[0] = nb0;  // 2^-10 inj
            s1 = nb1 * nb1 / bv[1] * (1.0f / 1024.0f); bv[1] = nb1;
            s2 = nb2 * nb2 / bv[2] * (1.0f / 1024.0f); bv[2] = nb2;
            s3 = nb3 * nb3 / bv[3] * (1.0f / 1024.0f); bv[3] = nb3;
        }

        // row partials over own 4 cols
        float v[32];
#pragma unroll
        for (int i = 0; i < 32; ++i)
            v[i] = E[i][0] * s0 + E[i][1] * s1 + E[i][2] * s2 + E[i][3] * s3;
        // register-splitting butterfly: lane l -> row (l&31) over 64 lanes
#pragma unroll
        for (int st = 0; st < 5; ++st) {
            const int m = 1 << st;
            const bool up = (lane & m) != 0;
#pragma unroll
            for (int i = 0; i < (16 >> st); ++i) {
                float x = v[2 * i], y = v[2 * i + 1];
                float send = up ? x : y;
                float keep = up ? y : x;
                v[i] = keep + __shfl_xor(send, m, 64);
            }
        }
        v[0] += __shfl_xor(v[0], 32, 64);
        if (lane < 32) rws[rs][lane] = v[0];
        __syncthreads();
        if (tid < 32)
            aLs[tid] = 1.0f / (1024.0f * (rws[0][tid] + rws[1][tid] +
                                          rws[2][tid] + rws[3][tid]));
        __syncthreads();
#pragma unroll
        for (int q = 0; q < 8; ++q) {
            float4 a4 = *(const float4*)&aLs[4 * q];
            al[4*q] = a4.x; al[4*q+1] = a4.y; al[4*q+2] = a4.z; al[4*q+3] = a4.w;
        }

        // col phase: fully thread-local, direct atomicAdd (replica g&3)
        float p0 = 0.f, p1 = 0.f, p2 = 0.f, p3 = 0.f;
#pragma unroll
        for (int i = 0; i < 32; ++i) {
            float ai = al[i];
            p0 += E[i][0] * ai; p1 += E[i][1] * ai;
            p2 += E[i][2] * ai; p3 += E[i][3] * ai;
        }
        float* wb = cvec + (t % 3) * (NREP * 1024) + (g & 3) * 1024 + j0;
        atomicAdd(wb + 0, p0);
        atomicAdd(wb + 1, p1);
        atomicAdd(wb + 2, p2);
        atomicAdd(wb + 3, p3);

        if (t < NIT - 1) {  // E_{t+1} = E_t * E1 (overlaps add drain)
#pragma unroll
            for (int i = 0; i < 32; ++i) {
                E[i][0] *= E1[i][0]; E[i][1] *= E1[i][1];
                E[i][2] *= E1[i][2]; E[i][3] *= E1[i][3];
            }
        }
        __syncthreads();  // per-wave vmcnt(0) drain: all 1024 adds at LLC
        if (tid == 0)
            __hip_atomic_fetch_add(&cnt[(g >> 3) * 32], 1u, __ATOMIC_RELAXED,
                                   __HIP_MEMORY_SCOPE_AGENT);
    }

    // ---------------- epilogue: E = exp(50*Cl), al = round-49 a -------------
    wavepoll(cnt, lane, (unsigned)NIT * 8u);
    float bl[4];
    {   // final b for own 4 cols (round-49 col sums)
        const ull* rb = (const ull*)(cvec + ((NIT - 1) % 3) * (NREP * 1024)) + (j0 >> 1);
        ull a0 = __hip_atomic_load(rb + 0,    __ATOMIC_RELAXED, __HIP_MEMORY_SCOPE_AGENT);
        ull a1 = __hip_atomic_load(rb + 1,    __ATOMIC_RELAXED, __HIP_MEMORY_SCOPE_AGENT);
        ull b0 = __hip_atomic_load(rb + 512,  __ATOMIC_RELAXED, __HIP_MEMORY_SCOPE_AGENT);
        ull b1 = __hip_atomic_load(rb + 513,  __ATOMIC_RELAXED, __HIP_MEMORY_SCOPE_AGENT);
        ull c0 = __hip_atomic_load(rb + 1024, __ATOMIC_RELAXED, __HIP_MEMORY_SCOPE_AGENT);
        ull c1 = __hip_atomic_load(rb + 1025, __ATOMIC_RELAXED, __HIP_MEMORY_SCOPE_AGENT);
        ull d0 = __hip_atomic_load(rb + 1536, __ATOMIC_RELAXED, __HIP_MEMORY_SCOPE_AGENT);
        ull d1 = __hip_atomic_load(rb + 1537, __ATOMIC_RELAXED, __HIP_MEMORY_SCOPE_AGENT);
        bl[0] = 1.0f / (f_lo(a0) + f_lo(b0) + f_lo(c0) + f_lo(d0));
        bl[1] = 1.0f / (f_hi(a0) + f_hi(b0) + f_hi(c0) + f_hi(d0));
        bl[2] = 1.0f / (f_lo(a1) + f_lo(b1) + f_lo(c1) + f_lo(d1));
        bl[3] = 1.0f / (f_hi(a1) + f_hi(b1) + f_hi(c1) + f_hi(d1));
    }

    // P(k,A), R(k,B): reduce own-4-col partials over the 4 lanes per A-block
    float* Ps = PsRs;           // [32][64]
    float* Rs = PsRs + 2048;    // [32][64]
    float Pl[32], Rl[32];
#pragma unroll
    for (int k = 0; k < 32; ++k) {
        Pl[k] = Pp[k];
        Rl[k] = E[k][0] * bl[0] + E[k][1] * bl[1] +
                E[k][2] * bl[2] + E[k][3] * bl[3];
    }
#pragma unroll
    for (int m = 1; m < 4; m <<= 1)
#pragma unroll
        for (int k = 0; k < 32; ++k) {
            Pl[k] += __shfl_xor(Pl[k], m, 64);
            Rl[k] += __shfl_xor(Rl[k], m, 64);
        }
    if ((lane & 3) == 0) {
        int A = rs * 16 + (lane >> 2);
#pragma unroll
        for (int k = 0; k < 32; ++k) {
            Ps[k * 64 + A] = -Pl[k];          // C = -Cl
            Rs[k * 64 + A] = al[k] * Rl[k];   // al = round-49 a
        }
    }
    __syncthreads();

    // G partial (this WG's 32 k-rows) -> atomicAdd into zeroed d_out
    float Rk[32];
#pragma unroll
    for (int k = 0; k < 32; ++k) Rk[k] = Rs[k * 64 + lane];  // B = lane
    const float sc = 1.0f / (256.0f * 1024.0f);
    float tsum = 0.0f;
#pragma unroll
    for (int q = 0; q < 16; ++q) {
        int o = tid + 256 * q;
        int A = 4 * q + rs;                  // = o >> 6
        float acc = 0.0f;
#pragma unroll
        for (int k = 0; k < 32; ++k) acc += Ps[k * 64 + A] * Rk[k];
        float val = acc * sc;
        atomicAdd(out + o, val);
        if (A == lane) tsum += val;
    }
#pragma unroll
    for (int m = 1; m < 64; m <<= 1) tsum += __shfl_xor(tsum, m, 64);
    if (lane == 0) twv[rs] = tsum;
    __syncthreads();
    if (tid == 0) atomicAdd(out + 4096, twv[0] + twv[1] + twv[2] + twv[3]);
}

// ---------------------------------------------------------------------------
extern "C" void kernel_launch(void* const* d_in, const int* in_sizes, int n_in,
                              void* d_out, int out_size, void* d_ws, size_t ws_size,
                              hipStream_t stream) {
    const float* X = (const float*)d_in[0];  // t_prob [1024,512]
    const float* Y = (const float*)d_in[1];  // v_prob [1024,512]
    float* out = (float*)d_out;              // [64*64 + 1]
    float* ws  = (float*)d_ws;

    // zero cvec + padded counters (ws poisoned each call), zero d_out
    (void)hipMemsetAsync((char*)d_ws + (size_t)CVEC_OFF * 4, 0,
                         (3 * NREP * 1024 + 128) * 4, stream);
    (void)hipMemsetAsync(d_out, 0, (size_t)out_size * 4, stream);

    k_gemm<<<dim3(16, 16), 256, 0, stream>>>(X, Y, ws);
    k_ipot<<<NWG, TPB, 0, stream>>>(ws, out);
}